// Round 20
// baseline (166.753 us; speedup 1.0000x reference)
//
#include <hip/hip_runtime.h>
#include <stdint.h>

#define BB 2
#define TT 2048
#define CCx 1024
#define HH 16
#define DD 64
#define MM (BB*TT)      // 4096
#define C3 (3*CCx)      // 3072

using u16 = unsigned short;
typedef __attribute__((ext_vector_type(8))) short short8;
typedef __attribute__((ext_vector_type(4))) float f32x4;

__device__ __forceinline__ float bf2f(u16 u){
  union { unsigned int i; float f; } v; v.i = ((unsigned int)u) << 16; return v.f;
}
__device__ __forceinline__ u16 f2bf(float f){
  union { float f; unsigned int u; } v; v.f = f;
  unsigned int r = v.u + 0x7fffu + ((v.u >> 16) & 1u);
  return (u16)(r >> 16);
}

// D = A(16x32)*B(32x16)+C, bf16 in, fp32 out.
__device__ __forceinline__ f32x4 mfma16x16x32(short8 a, short8 b, f32x4 c){
  return __builtin_amdgcn_mfma_f32_16x16x32_bf16(a, b, c, 0, 0, 0);
}

typedef __attribute__((address_space(1))) unsigned int gu32;
typedef __attribute__((address_space(3))) unsigned int su32;
__device__ __forceinline__ void gload16(const void* g, void* l){
  __builtin_amdgcn_global_load_lds((gu32*)g, (su32*)l, 16, 0, 0);
}

// ---- DPP 16-lane-row reductions (VALU pipe, no LDS traffic) ----
template<int CTRL>
__device__ __forceinline__ float dpp_mov(float x){
  int xi = __builtin_bit_cast(int, x);
  int yi = __builtin_amdgcn_update_dpp(xi, xi, CTRL, 0xF, 0xF, true);
  return __builtin_bit_cast(float, yi);
}
__device__ __forceinline__ float dpp_max16(float x){
  x = fmaxf(x, dpp_mov<0xB1>(x));
  x = fmaxf(x, dpp_mov<0x4E>(x));
  x = fmaxf(x, dpp_mov<0x124>(x));
  x = fmaxf(x, dpp_mov<0x128>(x));
  return x;
}
__device__ __forceinline__ float dpp_sum16(float x){
  x += dpp_mov<0xB1>(x);
  x += dpp_mov<0x4E>(x);
  x += dpp_mov<0x124>(x);
  x += dpp_mov<0x128>(x);
  return x;
}

// ------- prep: weight transposes only. blocks 0..767 = w_attn, 768..1023 = w_proj
__global__ __launch_bounds__(256) void prep_k(const float* __restrict__ w_attn,
                                              u16* __restrict__ wT_attn,
                                              const float* __restrict__ w_proj,
                                              u16* __restrict__ wT_proj){
  __shared__ u16 t[64][65];
  const int bid = blockIdx.x;
  const int tid = threadIdx.x;
  const float* inv; u16* out; int R, Cc, bx, by;
  if (bid < 768){
    inv = w_attn; out = wT_attn; R = CCx; Cc = C3;
    bx = (bid % 48)*64; by = (bid / 48)*64;
  } else {
    const int b3 = bid - 768;
    inv = w_proj; out = wT_proj; R = CCx; Cc = CCx;
    bx = (b3 % 16)*64; by = (b3 / 16)*64;
  }
  const int tx = tid & 63, ty = tid >> 6;
  #pragma unroll
  for (int i = 0; i < 16; ++i){
    int r = ty + i*4;
    t[r][tx] = f2bf(inv[(size_t)(by+r)*Cc + bx+tx]);
  }
  __syncthreads();
  #pragma unroll
  for (int i = 0; i < 16; ++i){
    int r = ty + i*4;
    out[(size_t)(bx+r)*R + by+tx] = t[tx][r];
  }
}

// ---------------- GEMM (NT): C[M][N] = A[M][K]*BT[N][K]^T + bias ----------
// 128x128 tile, BK=64, 8 waves (each 32x64). A-operand: af32=1 -> A is f32,
// reg-staged with in-kernel cvt + swizzled ds_write (VSTORE pattern);
// af32=0 -> A bf16 via gload16. B always bf16 via gload16. XCD swizzle.
__global__ __launch_bounds__(512) void gemm_nt(const void* __restrict__ Ap, int af32,
                                               const u16* __restrict__ BT,
                                               const float* __restrict__ bias,
                                               void* __restrict__ Cmat,
                                               int M, int N, int K, int of32){
  __shared__ u16 lA[128*64];
  __shared__ u16 lB[128*64];
  const int tid  = threadIdx.x;
  const int lane = tid & 63;
  const int wave = tid >> 6;            // 0..7
  const int nwg = gridDim.x * gridDim.y;
  const int lin = blockIdx.y * gridDim.x + blockIdx.x;
  const int wg  = (lin & 7) * (nwg >> 3) + (lin >> 3);
  const int bm = wg % gridDim.x, bn = wg / gridDim.x;
  const int wm = (wave & 3) * 32;
  const int wn = (wave >> 2) * 64;
  const int ln15 = lane & 15, g = lane >> 4;

  f32x4 acc[2][4];
  #pragma unroll
  for (int i = 0; i < 2; ++i)
    #pragma unroll
    for (int j = 0; j < 4; ++j) acc[i][j] = (f32x4){0.f,0.f,0.f,0.f};

  const int trow = tid >> 3;            // 0..63
  const int c8l  = tid & 7;             // logical 16B-chunk for A f32 path
  const int tc8s = c8l ^ (trow & 7);    // pre-swizzled source chunk (gload path)
  const size_t arow0 = (size_t)(bm*128) * K;
  const size_t brow0 = (size_t)(bn*128) * K;
  const float* Af = (const float*)Ap;
  const u16*   Ab = (const u16*)Ap;

  for (int k0 = 0; k0 < K; k0 += 64) {
    __syncthreads();
    if (af32){
      #pragma unroll
      for (int c = 0; c < 2; ++c) {
        const int row = c*64 + trow;
        const float* p = Af + arow0 + (size_t)row*K + k0 + c8l*8;
        float4 a = *(const float4*)p, b = *(const float4*)(p+4);
        short8 v;
        v[0]=(short)f2bf(a.x); v[1]=(short)f2bf(a.y); v[2]=(short)f2bf(a.z); v[3]=(short)f2bf(a.w);
        v[4]=(short)f2bf(b.x); v[5]=(short)f2bf(b.y); v[6]=(short)f2bf(b.z); v[7]=(short)f2bf(b.w);
        *(short8*)((char*)lA + row*128 + ((c8l ^ (row & 7)) << 4)) = v;
        gload16(BT + brow0 + (size_t)row*K + k0 + tc8s*8,
                (char*)lB + c*8192 + (wave<<10));
      }
    } else {
      #pragma unroll
      for (int c = 0; c < 2; ++c) {
        const int row = c*64 + trow;
        const size_t roff = (size_t)row*K + k0 + tc8s*8;
        gload16(Ab + arow0 + roff, (char*)lA + c*8192 + (wave<<10));
        gload16(BT + brow0 + roff, (char*)lB + c*8192 + (wave<<10));
      }
    }
    asm volatile("s_waitcnt vmcnt(0)" ::: "memory");
    __syncthreads();

    short8 af[2][2], bfr[4][2];
    #pragma unroll
    for (int mf = 0; mf < 2; ++mf)
      #pragma unroll
      for (int kc = 0; kc < 2; ++kc) {
        const int r = wm + mf*16 + ln15;
        const int cb = (kc*64 + (g << 4)) ^ ((r & 7) << 4);
        af[mf][kc] = *(const short8*)((const char*)lA + r*128 + cb);
      }
    #pragma unroll
    for (int nf = 0; nf < 4; ++nf)
      #pragma unroll
      for (int kc = 0; kc < 2; ++kc) {
        const int r = wn + nf*16 + ln15;
        const int cb = (kc*64 + (g << 4)) ^ ((r & 7) << 4);
        bfr[nf][kc] = *(const short8*)((const char*)lB + r*128 + cb);
      }
    #pragma unroll
    for (int kc = 0; kc < 2; ++kc)
      #pragma unroll
      for (int mf = 0; mf < 2; ++mf)
        #pragma unroll
        for (int nf = 0; nf < 4; ++nf)
          acc[mf][nf] = mfma16x16x32(af[mf][kc], bfr[nf][kc], acc[mf][nf]);
  }

  #pragma unroll
  for (int nf = 0; nf < 4; ++nf) {
    const int col = bn*128 + wn + nf*16 + ln15;
    const float bv = bias[col];
    #pragma unroll
    for (int mf = 0; mf < 2; ++mf) {
      #pragma unroll
      for (int r = 0; r < 4; ++r) {
        const int rowg = bm*128 + wm + mf*16 + g*4 + r;
        const float v = acc[mf][nf][r] + bv;
        if (of32) ((float*)Cmat)[(size_t)rowg*N + col] = v;
        else      ((u16*)Cmat)[(size_t)rowg*N + col] = f2bf(v);
      }
    }
  }
}

// -------- causal flash attention (r19: r13 + VALU diet) --------
#define LOG2E_S 0.1803369f   // log2(e) * 0.125
__global__ __launch_bounds__(512) void attn_k(const u16* __restrict__ qkv,
                                              u16* __restrict__ y){
  __shared__ u16 kb[2][64*64];
  __shared__ u16 vb[2][64*64];
  __shared__ u16 pls[8][16*64];
  const int tid  = threadIdx.x;
  const int lane = tid & 63;
  const int wave = tid >> 6;
  const int bx = blockIdx.x;
  const int jb = (bx < 8) ? bx : (23 - bx);
  const int bh = blockIdx.y;
  const int b = bh >> 4, h = bh & 15;
  const int ln15 = lane & 15, g = lane >> 4;
  const int sub = wave >> 2;
  const int wq  = wave & 3;
  const int jq  = sub ? (31 - jb) : jb;
  const int q0  = jq*64 + wq*16;
  const int ntw = sub ? (32 - jb) : (jb + 1);
  const int nt  = 32 - jb;
  const size_t base = (size_t)b * TT * C3;

  const int srow = tid >> 3;
  const int sc8  = tid & 7;
  const u16* ksrc0 = qkv + base + CCx + h*DD + (((sc8) ^ (srow & 7)) * 8);
  const u16* vsrc0 = qkv + base + 2*CCx + h*DD + sc8*8;
  char* plw = (char*)pls[wave];

  short8 qf[2];
  {
    const u16* qp = qkv + base + (size_t)(q0 + ln15)*C3 + h*DD + g*8;
    qf[0] = *(const short8*)qp;
    qf[1] = *(const short8*)(qp + 32);
  }

  f32x4 o[4]; float m[4], plsum[4];
  #pragma unroll
  for (int i = 0; i < 4; ++i){ o[i] = (f32x4){0.f,0.f,0.f,0.f}; m[i] = -1e30f; plsum[i] = 0.f; }

  short8 vreg;
  #define VSTORE(curb) do { \
    char* vd_ = (char*)vb + (curb)*8192; \
    _Pragma("unroll") \
    for (int i = 0; i < 8; ++i){ \
      const int d_ = sc8*8 + i; \
      const int sw_ = (i + sc8) & 7; \
      *(u16*)(vd_ + d_*128 + (((srow>>3) ^ sw_) << 4) + (srow & 7)*2) = (u16)vreg[i]; \
    } \
  } while(0)

  gload16(ksrc0 + (size_t)srow*C3, (char*)kb[0] + wave*1024);
  vreg = *(const short8*)(vsrc0 + (size_t)srow*C3);
  asm volatile("s_waitcnt vmcnt(0)" ::: "memory");
  VSTORE(0);
  __syncthreads();

  int cur = 0;
  for (int t = 0; t < nt; ++t){
    const int kv0 = t*64;
    const bool hn = (t + 1 < nt);
    if (hn){
      gload16(ksrc0 + (size_t)(kv0 + 64 + srow)*C3, (char*)kb[cur^1] + wave*1024);
      vreg = *(const short8*)(vsrc0 + (size_t)(kv0 + 64 + srow)*C3);
    }

    if (t < ntw){
      const char* kbc = (const char*)kb + cur*8192;
      f32x4 s[4];
      __builtin_amdgcn_s_setprio(1);
      #pragma unroll
      for (int kf = 0; kf < 4; ++kf){
        const int krow = kf*16 + ln15;
        short8 k0 = *(const short8*)(kbc + krow*128 + ((g*16)      ^ ((krow & 7)*16)));
        short8 k1 = *(const short8*)(kbc + krow*128 + ((64 + g*16) ^ ((krow & 7)*16)));
        f32x4 z = (f32x4){0.f,0.f,0.f,0.f};
        s[kf] = mfma16x16x32(qf[0], k0, z);
        s[kf] = mfma16x16x32(qf[1], k1, s[kf]);
      }
      __builtin_amdgcn_s_setprio(0);

      float tmax[4] = {-1e30f,-1e30f,-1e30f,-1e30f};
      if (t == ntw - 1){
        #pragma unroll
        for (int kf = 0; kf < 4; ++kf){
          const int key = kv0 + kf*16 + ln15;
          #pragma unroll
          for (int r = 0; r < 4; ++r){
            const int q = q0 + g*4 + r;
            float v = (key <= q) ? s[kf][r] : -1e30f;
            s[kf][r] = v;
            tmax[r] = fmaxf(tmax[r], v);
          }
        }
      } else {
        #pragma unroll
        for (int kf = 0; kf < 4; ++kf)
          #pragma unroll
          for (int r = 0; r < 4; ++r)
            tmax[r] = fmaxf(tmax[r], s[kf][r]);
      }
      bool need = false;
      #pragma unroll
      for (int r = 0; r < 4; ++r) need |= (tmax[r] > m[r] + 64.f);
      if (__any(need)){
        #pragma unroll
        for (int r = 0; r < 4; ++r){
          const float tr = dpp_max16(tmax[r]);
          const float nm = fmaxf(m[r], tr);
          const float fac = exp2f((m[r] - nm) * LOG2E_S);
          m[r] = nm; plsum[r] *= fac;
          #pragma unroll
          for (int db = 0; db < 4; ++db) o[db][r] *= fac;
        }
      }
      float mm[4];
      #pragma unroll
      for (int r = 0; r < 4; ++r) mm[r] = m[r]*LOG2E_S;
      #pragma unroll
      for (int r = 0; r < 4; ++r){
        const int qr = g*4 + r;
        char* rowp = plw + qr*128;
        const int swz = qr & 7;
        #pragma unroll
        for (int pk = 0; pk < 2; ++pk){
          const float pa_ = exp2f(fmaf(s[2*pk][r],   LOG2E_S, -mm[r]));
          const float pb_ = exp2f(fmaf(s[2*pk+1][r], LOG2E_S, -mm[r]));
          plsum[r] += pa_ + pb_;
          unsigned w;
          asm("v_cvt_pk_bf16_f32 %0, %1, %2" : "=v"(w) : "v"(pa_), "v"(pb_));
          const int hi8 = ln15 >> 3, lo7 = (ln15 & 7)*2;
          *(u16*)(rowp + (((4*pk   + hi8) ^ swz) << 4) + lo7) = (u16)w;
          *(u16*)(rowp + (((4*pk+2 + hi8) ^ swz) << 4) + lo7) = (u16)(w >> 16);
        }
      }
      asm volatile("s_waitcnt lgkmcnt(0)" ::: "memory");
      __builtin_amdgcn_sched_barrier(0);

      const char* vbc = (const char*)vb + cur*8192;
      __builtin_amdgcn_s_setprio(1);
      #pragma unroll
      for (int kc = 0; kc < 2; ++kc){
        const int ch = kc*4 + g;
        short8 pa = *(const short8*)(plw + ln15*128 + ((ch ^ (ln15 & 7)) << 4));
        #pragma unroll
        for (int db = 0; db < 4; ++db){
          const int vd = db*16 + ln15;
          const int swv = ((vd & 7) + ((vd >> 3) & 7)) & 7;
          short8 vbr = *(const short8*)(vbc + vd*128 + ((ch ^ swv) << 4));
          o[db] = mfma16x16x32(pa, vbr, o[db]);
        }
      }
      __builtin_amdgcn_s_setprio(0);
    }

    if (hn){
      asm volatile("s_waitcnt vmcnt(0)" ::: "memory");
      VSTORE(cur^1);
    }
    __syncthreads();
    cur ^= 1;
  }

  float inv[4];
  #pragma unroll
  for (int r = 0; r < 4; ++r) inv[r] = 1.0f / dpp_sum16(plsum[r]);
  #pragma unroll
  for (int db = 0; db < 4; ++db){
    #pragma unroll
    for (int r = 0; r < 4; ++r){
      y[(size_t)(b*TT + q0 + g*4 + r)*CCx + h*DD + db*16 + ln15] = f2bf(o[db][r] * inv[r]);
    }
  }
  #undef VSTORE
}

extern "C" void kernel_launch(void* const* d_in, const int* in_sizes, int n_in,
                              void* d_out, int out_size, void* d_ws, size_t ws_size,
                              hipStream_t stream) {
  const float *x = nullptr, *w_attn = nullptr, *b_attn = nullptr,
              *w_proj = nullptr, *b_proj = nullptr;
  for (int i = 0; i < n_in; ++i) {
    switch (in_sizes[i]) {
      case MM*CCx:  x      = (const float*)d_in[i]; break;
      case C3*CCx:  w_attn = (const float*)d_in[i]; break;
      case C3:      b_attn = (const float*)d_in[i]; break;
      case CCx*CCx: w_proj = (const float*)d_in[i]; break;
      case CCx:     b_proj = (const float*)d_in[i]; break;
    }
  }
  float* out = (float*)d_out;

  char* ws = (char*)d_ws;
  u16* wT_attn = (u16*)ws;                              // [3072][1024]
  u16* wT_proj = wT_attn + (size_t)C3*CCx;              // [1024][1024]
  u16* qkv     = wT_proj + (size_t)CCx*CCx;             // [4096][3072]
  u16* ybuf    = qkv + (size_t)MM*C3;                   // [4096][1024]

  prep_k<<<1024, 256, 0, stream>>>(w_attn, wT_attn, w_proj, wT_proj);
  gemm_nt<<<dim3(MM/128, C3/128), 512, 0, stream>>>(x, 1, wT_attn, b_attn, qkv, MM, C3, CCx, 0);
  attn_k<<<dim3(16, BB*HH), 512, 0, stream>>>(qkv, ybuf);
  gemm_nt<<<dim3(MM/128, CCx/128), 512, 0, stream>>>(ybuf, 0, wT_proj, b_proj, out, MM, CCx, CCx, 1);
}

// Round 21
// 127.597 us; speedup vs baseline: 1.3069x; 1.3069x over previous
//
#include <hip/hip_runtime.h>
#include <stdint.h>

#define BB 2
#define TT 2048
#define CCx 1024
#define HH 16
#define DD 64
#define MM (BB*TT)      // 4096
#define C3 (3*CCx)      // 3072

using u16 = unsigned short;
typedef __attribute__((ext_vector_type(8))) short short8;
typedef __attribute__((ext_vector_type(4))) float f32x4;

__device__ __forceinline__ float bf2f(u16 u){
  union { unsigned int i; float f; } v; v.i = ((unsigned int)u) << 16; return v.f;
}
__device__ __forceinline__ u16 f2bf(float f){
  union { float f; unsigned int u; } v; v.f = f;
  unsigned int r = v.u + 0x7fffu + ((v.u >> 16) & 1u);
  return (u16)(r >> 16);
}

// D = A(16x32)*B(32x16)+C, bf16 in, fp32 out.
__device__ __forceinline__ f32x4 mfma16x16x32(short8 a, short8 b, f32x4 c){
  return __builtin_amdgcn_mfma_f32_16x16x32_bf16(a, b, c, 0, 0, 0);
}

typedef __attribute__((address_space(1))) unsigned int gu32;
typedef __attribute__((address_space(3))) unsigned int su32;
__device__ __forceinline__ void gload16(const void* g, void* l){
  __builtin_amdgcn_global_load_lds((gu32*)g, (su32*)l, 16, 0, 0);
}

// ---- DPP 16-lane-row reductions (VALU pipe, no LDS traffic) ----
template<int CTRL>
__device__ __forceinline__ float dpp_mov(float x){
  int xi = __builtin_bit_cast(int, x);
  int yi = __builtin_amdgcn_update_dpp(xi, xi, CTRL, 0xF, 0xF, true);
  return __builtin_bit_cast(float, yi);
}
__device__ __forceinline__ float dpp_max16(float x){
  x = fmaxf(x, dpp_mov<0xB1>(x));
  x = fmaxf(x, dpp_mov<0x4E>(x));
  x = fmaxf(x, dpp_mov<0x124>(x));
  x = fmaxf(x, dpp_mov<0x128>(x));
  return x;
}
__device__ __forceinline__ float dpp_sum16(float x){
  x += dpp_mov<0xB1>(x);
  x += dpp_mov<0x4E>(x);
  x += dpp_mov<0x124>(x);
  x += dpp_mov<0x128>(x);
  return x;
}

// ------- fused prep: x cvt (blocks 0..2047), w_attn T (2048..2815),
//         w_proj T (2816..3071). All paths 256 threads. -------
__global__ __launch_bounds__(256) void prep_k(const float* __restrict__ x,
                                              u16* __restrict__ xb,
                                              const float* __restrict__ w_attn,
                                              u16* __restrict__ wT_attn,
                                              const float* __restrict__ w_proj,
                                              u16* __restrict__ wT_proj){
  __shared__ u16 t[64][65];
  const int bid = blockIdx.x;
  const int tid = threadIdx.x;
  if (bid < 2048){
    const int i = bid*256 + tid;            // n8 = 2048*256 exactly
    const float* p = x + (size_t)i*8;
    float4 a = *(const float4*)p, b = *(const float4*)(p+4);
    short8 v;
    v[0]=(short)f2bf(a.x); v[1]=(short)f2bf(a.y); v[2]=(short)f2bf(a.z); v[3]=(short)f2bf(a.w);
    v[4]=(short)f2bf(b.x); v[5]=(short)f2bf(b.y); v[6]=(short)f2bf(b.z); v[7]=(short)f2bf(b.w);
    *(short8*)(xb + (size_t)i*8) = v;
    return;
  }
  const float* inv; u16* out; int R, Cc, bx, by;
  if (bid < 2048 + 768){
    const int b2 = bid - 2048;
    inv = w_attn; out = wT_attn; R = CCx; Cc = C3;
    bx = (b2 % 48)*64; by = (b2 / 48)*64;
  } else {
    const int b3 = bid - 2816;
    inv = w_proj; out = wT_proj; R = CCx; Cc = CCx;
    bx = (b3 % 16)*64; by = (b3 / 16)*64;
  }
  const int tx = tid & 63, ty = tid >> 6;
  #pragma unroll
  for (int i = 0; i < 16; ++i){
    int r = ty + i*4;
    t[r][tx] = f2bf(inv[(size_t)(by+r)*Cc + bx+tx]);
  }
  __syncthreads();
  #pragma unroll
  for (int i = 0; i < 16; ++i){
    int r = ty + i*4;
    out[(size_t)(bx+r)*R + by+tx] = t[tx][r];
  }
}

// ---------------- GEMM (NT): C[M][N] = A[M][K]*BT[N][K]^T + bias ----------
// 128x128 tile, BK=64, 8 waves (each 32x64 output). XCD-bijective swizzle.
__global__ __launch_bounds__(512) void gemm_nt(const u16* __restrict__ A,
                                               const u16* __restrict__ BT,
                                               const float* __restrict__ bias,
                                               void* __restrict__ Cmat,
                                               int M, int N, int K, int of32){
  __shared__ u16 lA[128*64];
  __shared__ u16 lB[128*64];
  const int tid  = threadIdx.x;
  const int lane = tid & 63;
  const int wave = tid >> 6;            // 0..7
  const int nwg = gridDim.x * gridDim.y;
  const int lin = blockIdx.y * gridDim.x + blockIdx.x;
  const int wg  = (lin & 7) * (nwg >> 3) + (lin >> 3);
  const int bm = wg % gridDim.x, bn = wg / gridDim.x;
  const int wm = (wave & 3) * 32;
  const int wn = (wave >> 2) * 64;
  const int ln15 = lane & 15, g = lane >> 4;

  f32x4 acc[2][4];
  #pragma unroll
  for (int i = 0; i < 2; ++i)
    #pragma unroll
    for (int j = 0; j < 4; ++j) acc[i][j] = (f32x4){0.f,0.f,0.f,0.f};

  const int trow = tid >> 3;            // 0..63
  const int tc8s = (tid & 7) ^ (trow & 7);
  const size_t arow0 = (size_t)(bm*128) * K;
  const size_t brow0 = (size_t)(bn*128) * K;

  for (int k0 = 0; k0 < K; k0 += 64) {
    __syncthreads();
    #pragma unroll
    for (int c = 0; c < 2; ++c) {
      const int row = c*64 + trow;
      const size_t roff = (size_t)row*K + k0 + tc8s*8;
      gload16(A + arow0 + roff, (char*)lA + c*8192 + (wave<<10));
      gload16(BT + brow0 + roff, (char*)lB + c*8192 + (wave<<10));
    }
    asm volatile("s_waitcnt vmcnt(0)" ::: "memory");
    __syncthreads();

    short8 af[2][2], bfr[4][2];
    #pragma unroll
    for (int mf = 0; mf < 2; ++mf)
      #pragma unroll
      for (int kc = 0; kc < 2; ++kc) {
        const int r = wm + mf*16 + ln15;
        const int cb = (kc*64 + (g << 4)) ^ ((r & 7) << 4);
        af[mf][kc] = *(const short8*)((const char*)lA + r*128 + cb);
      }
    #pragma unroll
    for (int nf = 0; nf < 4; ++nf)
      #pragma unroll
      for (int kc = 0; kc < 2; ++kc) {
        const int r = wn + nf*16 + ln15;
        const int cb = (kc*64 + (g << 4)) ^ ((r & 7) << 4);
        bfr[nf][kc] = *(const short8*)((const char*)lB + r*128 + cb);
      }
    #pragma unroll
    for (int kc = 0; kc < 2; ++kc)
      #pragma unroll
      for (int mf = 0; mf < 2; ++mf)
        #pragma unroll
        for (int nf = 0; nf < 4; ++nf)
          acc[mf][nf] = mfma16x16x32(af[mf][kc], bfr[nf][kc], acc[mf][nf]);
  }

  #pragma unroll
  for (int nf = 0; nf < 4; ++nf) {
    const int col = bn*128 + wn + nf*16 + ln15;
    const float bv = bias[col];
    #pragma unroll
    for (int mf = 0; mf < 2; ++mf) {
      #pragma unroll
      for (int r = 0; r < 4; ++r) {
        const int rowg = bm*128 + wm + mf*16 + g*4 + r;
        const float v = acc[mf][nf][r] + bv;
        if (of32) ((float*)Cmat)[(size_t)rowg*N + col] = v;
        else      ((u16*)Cmat)[(size_t)rowg*N + col] = f2bf(v);
      }
    }
  }
}

// -------- causal flash attention (r19: r13 + VALU diet) --------
#define LOG2E_S 0.1803369f   // log2(e) * 0.125
__global__ __launch_bounds__(512) void attn_k(const u16* __restrict__ qkv,
                                              u16* __restrict__ y){
  __shared__ u16 kb[2][64*64];
  __shared__ u16 vb[2][64*64];
  __shared__ u16 pls[8][16*64];
  const int tid  = threadIdx.x;
  const int lane = tid & 63;
  const int wave = tid >> 6;
  const int bx = blockIdx.x;
  const int jb = (bx < 8) ? bx : (23 - bx);
  const int bh = blockIdx.y;
  const int b = bh >> 4, h = bh & 15;
  const int ln15 = lane & 15, g = lane >> 4;
  const int sub = wave >> 2;
  const int wq  = wave & 3;
  const int jq  = sub ? (31 - jb) : jb;
  const int q0  = jq*64 + wq*16;
  const int ntw = sub ? (32 - jb) : (jb + 1);
  const int nt  = 32 - jb;
  const size_t base = (size_t)b * TT * C3;

  const int srow = tid >> 3;
  const int sc8  = tid & 7;
  const u16* ksrc0 = qkv + base + CCx + h*DD + (((sc8) ^ (srow & 7)) * 8);
  const u16* vsrc0 = qkv + base + 2*CCx + h*DD + sc8*8;
  char* plw = (char*)pls[wave];

  short8 qf[2];
  {
    const u16* qp = qkv + base + (size_t)(q0 + ln15)*C3 + h*DD + g*8;
    qf[0] = *(const short8*)qp;
    qf[1] = *(const short8*)(qp + 32);
  }

  f32x4 o[4]; float m[4], plsum[4];
  #pragma unroll
  for (int i = 0; i < 4; ++i){ o[i] = (f32x4){0.f,0.f,0.f,0.f}; m[i] = -1e30f; plsum[i] = 0.f; }

  short8 vreg;
  #define VSTORE(curb) do { \
    char* vd_ = (char*)vb + (curb)*8192; \
    _Pragma("unroll") \
    for (int i = 0; i < 8; ++i){ \
      const int d_ = sc8*8 + i; \
      const int sw_ = (i + sc8) & 7; \
      *(u16*)(vd_ + d_*128 + (((srow>>3) ^ sw_) << 4) + (srow & 7)*2) = (u16)vreg[i]; \
    } \
  } while(0)

  gload16(ksrc0 + (size_t)srow*C3, (char*)kb[0] + wave*1024);
  vreg = *(const short8*)(vsrc0 + (size_t)srow*C3);
  asm volatile("s_waitcnt vmcnt(0)" ::: "memory");
  VSTORE(0);
  __syncthreads();

  int cur = 0;
  for (int t = 0; t < nt; ++t){
    const int kv0 = t*64;
    const bool hn = (t + 1 < nt);
    if (hn){
      gload16(ksrc0 + (size_t)(kv0 + 64 + srow)*C3, (char*)kb[cur^1] + wave*1024);
      vreg = *(const short8*)(vsrc0 + (size_t)(kv0 + 64 + srow)*C3);
    }

    if (t < ntw){
      const char* kbc = (const char*)kb + cur*8192;
      f32x4 s[4];
      __builtin_amdgcn_s_setprio(1);
      #pragma unroll
      for (int kf = 0; kf < 4; ++kf){
        const int krow = kf*16 + ln15;
        short8 k0 = *(const short8*)(kbc + krow*128 + ((g*16)      ^ ((krow & 7)*16)));
        short8 k1 = *(const short8*)(kbc + krow*128 + ((64 + g*16) ^ ((krow & 7)*16)));
        f32x4 z = (f32x4){0.f,0.f,0.f,0.f};
        s[kf] = mfma16x16x32(qf[0], k0, z);
        s[kf] = mfma16x16x32(qf[1], k1, s[kf]);
      }
      __builtin_amdgcn_s_setprio(0);

      float tmax[4] = {-1e30f,-1e30f,-1e30f,-1e30f};
      if (t == ntw - 1){
        #pragma unroll
        for (int kf = 0; kf < 4; ++kf){
          const int key = kv0 + kf*16 + ln15;
          #pragma unroll
          for (int r = 0; r < 4; ++r){
            const int q = q0 + g*4 + r;
            float v = (key <= q) ? s[kf][r] : -1e30f;
            s[kf][r] = v;
            tmax[r] = fmaxf(tmax[r], v);
          }
        }
      } else {
        #pragma unroll
        for (int kf = 0; kf < 4; ++kf)
          #pragma unroll
          for (int r = 0; r < 4; ++r)
            tmax[r] = fmaxf(tmax[r], s[kf][r]);
      }
      bool need = false;
      #pragma unroll
      for (int r = 0; r < 4; ++r) need |= (tmax[r] > m[r] + 64.f);
      if (__any(need)){
        #pragma unroll
        for (int r = 0; r < 4; ++r){
          const float tr = dpp_max16(tmax[r]);
          const float nm = fmaxf(m[r], tr);
          const float fac = exp2f((m[r] - nm) * LOG2E_S);
          m[r] = nm; plsum[r] *= fac;
          #pragma unroll
          for (int db = 0; db < 4; ++db) o[db][r] *= fac;
        }
      }
      float mm[4];
      #pragma unroll
      for (int r = 0; r < 4; ++r) mm[r] = m[r]*LOG2E_S;
      #pragma unroll
      for (int r = 0; r < 4; ++r){
        const int qr = g*4 + r;
        char* rowp = plw + qr*128;
        const int swz = qr & 7;
        #pragma unroll
        for (int pk = 0; pk < 2; ++pk){
          const float pa_ = exp2f(fmaf(s[2*pk][r],   LOG2E_S, -mm[r]));
          const float pb_ = exp2f(fmaf(s[2*pk+1][r], LOG2E_S, -mm[r]));
          plsum[r] += pa_ + pb_;
          unsigned w;
          asm("v_cvt_pk_bf16_f32 %0, %1, %2" : "=v"(w) : "v"(pa_), "v"(pb_));
          const int hi8 = ln15 >> 3, lo7 = (ln15 & 7)*2;
          *(u16*)(rowp + (((4*pk   + hi8) ^ swz) << 4) + lo7) = (u16)w;
          *(u16*)(rowp + (((4*pk+2 + hi8) ^ swz) << 4) + lo7) = (u16)(w >> 16);
        }
      }
      asm volatile("s_waitcnt lgkmcnt(0)" ::: "memory");
      __builtin_amdgcn_sched_barrier(0);

      const char* vbc = (const char*)vb + cur*8192;
      __builtin_amdgcn_s_setprio(1);
      #pragma unroll
      for (int kc = 0; kc < 2; ++kc){
        const int ch = kc*4 + g;
        short8 pa = *(const short8*)(plw + ln15*128 + ((ch ^ (ln15 & 7)) << 4));
        #pragma unroll
        for (int db = 0; db < 4; ++db){
          const int vd = db*16 + ln15;
          const int swv = ((vd & 7) + ((vd >> 3) & 7)) & 7;
          short8 vbr = *(const short8*)(vbc + vd*128 + ((ch ^ swv) << 4));
          o[db] = mfma16x16x32(pa, vbr, o[db]);
        }
      }
      __builtin_amdgcn_s_setprio(0);
    }

    if (hn){
      asm volatile("s_waitcnt vmcnt(0)" ::: "memory");
      VSTORE(cur^1);
    }
    __syncthreads();
    cur ^= 1;
  }

  float inv[4];
  #pragma unroll
  for (int r = 0; r < 4; ++r) inv[r] = 1.0f / dpp_sum16(plsum[r]);
  #pragma unroll
  for (int db = 0; db < 4; ++db){
    #pragma unroll
    for (int r = 0; r < 4; ++r){
      y[(size_t)(b*TT + q0 + g*4 + r)*CCx + h*DD + db*16 + ln15] = f2bf(o[db][r] * inv[r]);
    }
  }
  #undef VSTORE
}

extern "C" void kernel_launch(void* const* d_in, const int* in_sizes, int n_in,
                              void* d_out, int out_size, void* d_ws, size_t ws_size,
                              hipStream_t stream) {
  const float *x = nullptr, *w_attn = nullptr, *b_attn = nullptr,
              *w_proj = nullptr, *b_proj = nullptr;
  for (int i = 0; i < n_in; ++i) {
    switch (in_sizes[i]) {
      case MM*CCx:  x      = (const float*)d_in[i]; break;
      case C3*CCx:  w_attn = (const float*)d_in[i]; break;
      case C3:      b_attn = (const float*)d_in[i]; break;
      case CCx*CCx: w_proj = (const float*)d_in[i]; break;
      case CCx:     b_proj = (const float*)d_in[i]; break;
    }
  }
  float* out = (float*)d_out;

  char* ws = (char*)d_ws;
  u16* xb      = (u16*)ws;
  u16* wT_attn = xb + (size_t)MM*CCx;
  u16* wT_proj = wT_attn + (size_t)C3*CCx;
  u16* qkv     = wT_proj + (size_t)CCx*CCx;
  u16* ybuf    = qkv + (size_t)MM*C3;

  prep_k<<<3072, 256, 0, stream>>>(x, xb, w_attn, wT_attn, w_proj, wT_proj);
  gemm_nt<<<dim3(MM/128, C3/128), 512, 0, stream>>>(xb, wT_attn, b_attn, qkv, MM, C3, CCx, 0);
  attn_k<<<dim3(16, BB*HH), 512, 0, stream>>>(qkv, ybuf);
  gemm_nt<<<dim3(MM/128, CCx/128), 512, 0, stream>>>(ybuf, wT_proj, b_proj, out, MM, CCx, CCx, 1);
}